// Round 10
// baseline (392.992 us; speedup 1.0000x reference)
//
#include <hip/hip_runtime.h>
#include <math.h>

// Fused AntiAliasActivation: up2 (12-tap polyphase) -> snake -> down2 (12-tap)
// x: (B=16, C=512, T=4096) fp32, out: same shape.
//
// R10: R9 (W=8, est. 72us kernel, beat the 80us harness memset) with
// __launch_bounds__(NT, 8): force VGPR <= 64 so each SIMD can hold the
// full 8-wave residency. R9 compiled under (NT,4) = 128-VGPR budget;
// the allocator has no incentive to stay under 64 there, and R6's
// 50%-occupancy-at-VGPR-40 suggests it pads above the 64 boundary when
// given headroom. Live set at W=8 is ~46 VGPR (f[24]+acc[8]+temps;
// taps/ea/rb are wave-uniform -> SGPR), so the cap should not spill
// (compiler hit 40-44 on the larger W=16 body). Single-variable change.
//
// Phase-plane formulation (hardware-verified R3..R9):
//   E[s] = act( 2*sum_m x[clamp(s-3+m)]*u[11-2m] )   (yact[2s])
//   O[s] = act( 2*sum_m x[clamp(s-2+m)]*u[10-2m] )   (yact[2s+1])
//   out[o] = sum_m E[o-2+m]*d[2m+1] + sum_m O[o-3+m]*d[2m]
//   act(y) = y + rb*sin(y*ea)^2
// Per thread (o0 = global offset, W=8): f[j] = x[clamp(o0-8+j)],
// j=0..23 (6 aligned float4); activation i=0..12: ev=E[o0-2+i],
// ov=O[o0-3+i], window f[i+3..i+8]; contribution of i to acc[r]:
// r in [i-5,i]&[0,7], taps d[2(i-r)+1] (E), d[2(i-r)] (O).
// Row-edge clamps: lo thread (o0==0): skip i<2, patch acc[0]+=E[0]*
// (d0+d1+d2+d3), acc[1]+=E[0]*(d0+d1), ov:=ev at i=2. hi thread
// (o0==T-8): E[T] first appears at i=10 where ov=O[T-1] -> Rv=ov,
// ev:=ov at i=10; ev=ov:=Rv for i>=11.

#define T_LEN 4096
#define NT    256
#define W     8                  // outputs per thread
#define NA    13                 // activation pairs per thread (W+5)

__global__ __launch_bounds__(NT, 8) void aa_act_kernel(
    const float* __restrict__ x,
    const float* __restrict__ alpha,
    const float* __restrict__ beta,
    const float* __restrict__ upf,
    const float* __restrict__ downf,
    float* __restrict__ out,
    int C)
{
    const int t   = threadIdx.x;
    const int blk = blockIdx.x;
    const int row = blk >> 1;                  // 2 blocks per row
    const int o0  = ((blk & 1) << 11) | (t << 3);
    const int c   = row % C;

    const float* __restrict__ xr = x + (size_t)row * T_LEN;
    float* __restrict__ outr     = out + (size_t)row * T_LEN;

    // Uniform filter taps. Prescale up-filter by 2 (UP factor) — exact.
    float ue[6], uo[6], d[12];
#pragma unroll
    for (int m = 0; m < 6; ++m) {
        ue[m] = 2.0f * upf[11 - 2 * m];
        uo[m] = 2.0f * upf[10 - 2 * m];
    }
#pragma unroll
    for (int i = 0; i < 12; ++i) d[i] = downf[i];

    const float ea = __expf(alpha[c]);
    const float rb = 1.0f / (__expf(beta[c]) + 1e-9f);

    const bool lo = (o0 == 0);
    const bool hi = (o0 == T_LEN - W);

    // ---- x[o0-8 .. o0+15] -> f[0..23], SROA-friendly ----
    float f[24];
    if (!lo && !hi) {
        const float4* p = (const float4*)(xr + o0 - 8);  // global: cast ok
#pragma unroll
        for (int i = 0; i < 6; ++i) {
            float4 v = p[i];
            f[4*i+0] = v.x; f[4*i+1] = v.y; f[4*i+2] = v.z; f[4*i+3] = v.w;
        }
    } else {
        // row-edge threads: scalar clamped loads (up-conv edge pad)
#pragma unroll
        for (int i = 0; i < 24; ++i)
            f[i] = xr[min(max(o0 - 8 + i, 0), T_LEN - 1)];
    }

    float acc[W];
#pragma unroll
    for (int r = 0; r < W; ++r) acc[r] = 0.0f;

    float Rv = 0.0f;   // O[T-1] capture (hi lane only)

#pragma unroll
    for (int i = 0; i < NA; ++i) {
        // activation pair at rolling index i
        float ye = f[i + 3] * ue[0];
        ye = fmaf(f[i + 4], ue[1], ye);
        ye = fmaf(f[i + 5], ue[2], ye);
        ye = fmaf(f[i + 6], ue[3], ye);
        ye = fmaf(f[i + 7], ue[4], ye);
        ye = fmaf(f[i + 8], ue[5], ye);
        float yo = f[i + 3] * uo[0];
        yo = fmaf(f[i + 4], uo[1], yo);
        yo = fmaf(f[i + 5], uo[2], yo);
        yo = fmaf(f[i + 6], uo[3], yo);
        yo = fmaf(f[i + 7], uo[4], yo);
        yo = fmaf(f[i + 8], uo[5], yo);
        float se = __sinf(ye * ea);
        float so = __sinf(yo * ea);
        float ev = fmaf(rb * se, se, ye);
        float ov = fmaf(rb * so, so, yo);

        // ---- down-conv pad-clamp overrides (row edges) ----
        if (i == 10) {
            if (hi) { Rv = ov; ev = ov; }          // E[T] := O[T-1]
        }
        if (i >= 11) {
            if (hi) { ev = Rv; ov = Rv; }          // E/O[>T] := O[T-1]
        }
        if (i == 2) {
            if (lo) {
                // ev == E[0]; patch the skipped i=0,1 contributions
                acc[0] = fmaf(ev, d[0] + d[1] + d[2] + d[3], acc[0]);
                acc[1] = fmaf(ev, d[0] + d[1], acc[1]);
                ov = ev;                            // O[-1] := E[0]
            }
        }

        // ---- consume into accumulators: r in [i-5, i] & [0, W-1] ----
        const int rlo = (i - 5 > 0) ? (i - 5) : 0;
        const int rhi = (i < W - 1) ? i : (W - 1);
        if (i < 2) {
            if (!lo) {
#pragma unroll
                for (int r = rlo; r <= rhi; ++r)
                    acc[r] = fmaf(ev, d[2 * (i - r) + 1],
                             fmaf(ov, d[2 * (i - r)], acc[r]));
            }
        } else {
#pragma unroll
            for (int r = rlo; r <= rhi; ++r)
                acc[r] = fmaf(ev, d[2 * (i - r) + 1],
                         fmaf(ov, d[2 * (i - r)], acc[r]));
        }
    }

    // ---- store: compose float4 from components (SROA-friendly) ----
    float4* po = (float4*)(outr + o0);           // global: cast ok
    po[0] = make_float4(acc[0], acc[1], acc[2], acc[3]);
    po[1] = make_float4(acc[4], acc[5], acc[6], acc[7]);
}

extern "C" void kernel_launch(void* const* d_in, const int* in_sizes, int n_in,
                              void* d_out, int out_size, void* d_ws, size_t ws_size,
                              hipStream_t stream) {
    const float* x     = (const float*)d_in[0];
    const float* alpha = (const float*)d_in[1];
    const float* beta  = (const float*)d_in[2];
    const float* upf   = (const float*)d_in[3];
    const float* downf = (const float*)d_in[4];
    float* out = (float*)d_out;

    const int C    = in_sizes[1];             // 512
    const int rows = in_sizes[0] / T_LEN;     // B*C = 8192

    dim3 grid(rows * 2), block(NT);
    hipLaunchKernelGGL(aa_act_kernel, grid, block, 0, stream,
                       x, alpha, beta, upf, downf, out, C);
}